// Round 1
// baseline (6167.335 us; speedup 1.0000x reference)
//
#include <hip/hip_runtime.h>

typedef unsigned int  u32;
typedef unsigned short u16;
typedef short s16x8 __attribute__((ext_vector_type(8)));
typedef float f32x4 __attribute__((ext_vector_type(4)));

// Problem constants
#define BB 32
#define TT 512
#define HH 512
#define GG 1536          // 3H
#define MM 16384         // B*T

__device__ __forceinline__ u16 f2bf(float f) {
  u32 u = __builtin_bit_cast(u32, f);
  u = u + 0x7FFFu + ((u >> 16) & 1u);   // RNE
  return (u16)(u >> 16);
}
__device__ __forceinline__ float bf2f(u16 h) {
  return __builtin_bit_cast(float, (u32)h << 16);
}
__device__ __forceinline__ float sigmoidf_(float x) { return 1.f / (1.f + __expf(-x)); }
__device__ __forceinline__ float tanhf_(float x)    { return 1.f - 2.f / (__expf(2.f * x) + 1.f); }

// ---------------------------------------------------------------------------
// Fragment layout convention (mfma_f32_16x16x32_bf16), used consistently
// everywhere (any consistent K-permutation of A and B cancels):
//   A (MxK): lane l elem j -> A[16*mb + (l&15)][32*kb + (l>>4)*4 + (j&3) + 16*(j>>2)]
//   B (KxN): lane l elem j -> B[32*kb + (l>>4)*4 + (j&3) + 16*(j>>2)][16*nb + (l&15)]
//   D:       lane l reg  r -> D[(l>>4)*4 + r][l&15]            (m89-verified)
// Global fragment buffers: [blk][kb][lane(64)][elem(8)] bf16, 1KB per (blk,kb).
// ---------------------------------------------------------------------------

struct PrepP {
  const float *ctx;
  const float *wih0, *whh0, *bih0, *bhh0, *wih0r, *whh0r, *bih0r, *bhh0r;
  const float *wih1, *whh1, *bih1, *bhh1, *wih1r, *whh1r, *bih1r, *bhh1r;
  u16 *a0f, *w0f, *w1f, *whh;
  float *bgx, *bhn;
  u32 *ctr;
};

__global__ void prep_kernel(PrepP P) {
  const size_t NA0 = (size_t)MM * 512;          // 8,388,608  A0 frags (K=512)
  const size_t NW0 = (size_t)3072 * 512;        // 1,572,864  W0 frags
  const size_t NW1 = (size_t)3072 * 1024;       // 3,145,728  W1 frags
  const size_t NWH = (size_t)2 * 2 * GG * HH;   // 3,145,728  w_hh bf16 copies
  const size_t NBG = 2 * 2 * (size_t)GG;        // 6144
  const size_t NBN = 2 * 2 * (size_t)HH;        // 2048
  const size_t TOTAL = NA0 + NW0 + NW1 + NWH + NBG + NBN + 4;
  size_t stride = (size_t)gridDim.x * blockDim.x;
  for (size_t i = (size_t)blockIdx.x * blockDim.x + threadIdx.x; i < TOTAL; i += stride) {
    size_t e = i;
    if (e < NA0) {  // context -> A0 fragment buffer (bf16)
      int j = e & 7, l = (e >> 3) & 63, kb = (e >> 9) & 15, mb = (int)(e >> 13);
      int m = mb * 16 + (l & 15);
      int k = kb * 32 + ((l >> 4) << 2) + (j & 3) + ((j >> 2) << 4);
      P.a0f[e] = f2bf(P.ctx[(size_t)m * 512 + k]);
      continue;
    }
    e -= NA0;
    if (e < NW0) {  // w_ih layer0 (both dirs) -> B fragment buffer, N=3072, K=512
      int j = e & 7, l = (e >> 3) & 63, kb = (e >> 9) & 15, nb = (int)(e >> 13);
      int n = nb * 16 + (l & 15);
      int d = (n >= GG) ? 1 : 0, g = n - d * GG;
      int k = kb * 32 + ((l >> 4) << 2) + (j & 3) + ((j >> 2) << 4);
      const float* src = d ? P.wih0r : P.wih0;
      P.w0f[e] = f2bf(src[(size_t)g * 512 + k]);
      continue;
    }
    e -= NW0;
    if (e < NW1) {  // w_ih layer1, K=1024
      int j = e & 7, l = (e >> 3) & 63, kb = (e >> 9) & 31, nb = (int)(e >> 14);
      int n = nb * 16 + (l & 15);
      int d = (n >= GG) ? 1 : 0, g = n - d * GG;
      int k = kb * 32 + ((l >> 4) << 2) + (j & 3) + ((j >> 2) << 4);
      const float* src = d ? P.wih1r : P.wih1;
      P.w1f[e] = f2bf(src[(size_t)g * 1024 + k]);
      continue;
    }
    e -= NW1;
    if (e < NWH) {  // w_hh plain bf16 copies: [layer][dir][1536][512]
      size_t per = (size_t)GG * HH;
      int ld = (int)(e / per); size_t sub = e % per;
      const float* src = (ld == 0) ? P.whh0 : (ld == 1) ? P.whh0r : (ld == 2) ? P.whh1 : P.whh1r;
      P.whh[e] = f2bf(src[sub]);
      continue;
    }
    e -= NWH;
    if (e < NBG) {  // bias_gx[layer][dir][1536] = b_ih + (b_hh for r,z gates)
      int ld = (int)(e / GG), g = (int)(e % GG);
      const float* bi = (ld == 0) ? P.bih0 : (ld == 1) ? P.bih0r : (ld == 2) ? P.bih1 : P.bih1r;
      const float* bh = (ld == 0) ? P.bhh0 : (ld == 1) ? P.bhh0r : (ld == 2) ? P.bhh1 : P.bhh1r;
      P.bgx[e] = bi[g] + ((g < 1024) ? bh[g] : 0.f);
      continue;
    }
    e -= NBG;
    if (e < NBN) {  // bias_hn[layer][dir][512] = b_hh[2H + u]
      int ld = (int)(e / HH), u = (int)(e % HH);
      const float* bh = (ld == 0) ? P.bhh0 : (ld == 1) ? P.bhh0r : (ld == 2) ? P.bhh1 : P.bhh1r;
      P.bhn[e] = bh[1024 + u];
      continue;
    }
    e -= NBN;
    if (e < 4) P.ctr[e] = 0u;
  }
}

// ---------------------------------------------------------------------------
// Projection GEMM: C[M=16384][N=3072] = A[M][K] * W[K][N], bf16 MFMA, f32 out
// scattered into gx[dir][t][b][1536].  128x128 tile, 4 waves (2x2), BK=32.
// ---------------------------------------------------------------------------
template<bool GXF32>
__global__ __launch_bounds__(256, 2) void proj_kernel(const u16* __restrict__ A,
                                                      const u16* __restrict__ W,
                                                      void* __restrict__ gx, int KB) {
  __shared__ uint4 As4[512];
  __shared__ uint4 Bs4[512];
  const int tid = threadIdx.x;
  const int bm = blockIdx.x, bn = blockIdx.y;
  const int l = tid & 63, w = tid >> 6, wm = w >> 1, wn = w & 1;

  f32x4 acc[4][4];
#pragma unroll
  for (int i = 0; i < 4; ++i)
#pragma unroll
    for (int j = 0; j < 4; ++j) acc[i][j] = f32x4{0.f, 0.f, 0.f, 0.f};

  const uint4* GA = (const uint4*)A;
  const uint4* GB = (const uint4*)W;

  for (int kt = 0; kt < KB; ++kt) {
    __syncthreads();
#pragma unroll
    for (int c = 0; c < 2; ++c) {
      int idx = tid * 2 + c;
      int blk = idx >> 6, pos = idx & 63;
      As4[idx] = GA[((size_t)(bm * 8 + blk) * KB + kt) * 64 + pos];
      Bs4[idx] = GB[((size_t)(bn * 8 + blk) * KB + kt) * 64 + pos];
    }
    __syncthreads();
    s16x8 av[4], bv[4];
#pragma unroll
    for (int mf = 0; mf < 4; ++mf) av[mf] = ((const s16x8*)As4)[(wm * 4 + mf) * 64 + l];
#pragma unroll
    for (int nf = 0; nf < 4; ++nf) bv[nf] = ((const s16x8*)Bs4)[(wn * 4 + nf) * 64 + l];
#pragma unroll
    for (int mf = 0; mf < 4; ++mf)
#pragma unroll
      for (int nf = 0; nf < 4; ++nf)
        acc[mf][nf] = __builtin_amdgcn_mfma_f32_16x16x32_bf16(av[mf], bv[nf], acc[mf][nf], 0, 0, 0);
  }

#pragma unroll
  for (int mf = 0; mf < 4; ++mf)
#pragma unroll
    for (int nf = 0; nf < 4; ++nf)
#pragma unroll
      for (int r = 0; r < 4; ++r) {
        int m = bm * 128 + wm * 64 + mf * 16 + (l >> 4) * 4 + r;
        int n = bn * 128 + wn * 64 + nf * 16 + (l & 15);
        int b = m >> 9, t = m & 511;
        int d = (n >= GG) ? 1 : 0, g = n - d * GG;
        size_t o = ((size_t)(d * TT + t) * BB + b) * GG + g;
        float v = acc[mf][nf][r];
        if (GXF32) ((float*)gx)[o] = v;
        else       ((u16*)gx)[o] = f2bf(v);
      }
}

// ---------------------------------------------------------------------------
// Recurrence: 32 WGs (16 per direction), each owns 32 h-units x 32 batches.
// w_hh A-fragments in registers; h exchanged via fragment-layout global buffer
// (double-buffered); per-direction atomic-counter barrier per step.
// ---------------------------------------------------------------------------
__device__ __forceinline__ void wg_barrier(u32* c, u32 target) {
  __syncthreads();               // all lanes' stores drained (vmcnt 0 before s_barrier)
  if (threadIdx.x == 0) {
    __threadfence();             // release: write back L2 to coherence point
    __hip_atomic_fetch_add(c, 1u, __ATOMIC_RELAXED, __HIP_MEMORY_SCOPE_AGENT);
    while (__hip_atomic_load(c, __ATOMIC_RELAXED, __HIP_MEMORY_SCOPE_AGENT) < target) {}
    __threadfence();             // acquire: invalidate L1/L2 so h loads are fresh
  }
  __syncthreads();
}

template<bool GXF32, bool YF32>
__global__ __launch_bounds__(256, 1) void recur_kernel(
    const void* __restrict__ gx_, const u16* __restrict__ whh,
    const float* __restrict__ bgx, const float* __restrict__ bhn_,
    void* __restrict__ yout, float* __restrict__ finals,
    u16* __restrict__ hex, u32* __restrict__ ctr) {
  const int wg = blockIdx.x, d = wg >> 4, s = wg & 15;
  const int tid = threadIdx.x, l = tid & 63, w = tid >> 6;
  const int nt = w & 1, uh = w >> 1;
  const int l4 = l >> 4, lm = l & 15;
  const int b = nt * 16 + lm;
  const int u0 = s * 32 + uh * 16 + l4 * 4;   // first of this lane's 4 h-units (D-side)

  // --- gather w_hh A-fragments into registers (rows: g*32+u_off within slice) ---
  s16x8 af[3][16];
  const u16* wd = whh + (size_t)d * (GG * HH);
#pragma unroll
  for (int g = 0; g < 3; ++g) {
    const int row = g * 512 + s * 32 + uh * 16 + lm;     // A-side row uses lane&15
    const u16* rp = wd + (size_t)row * 512 + l4 * 4;
#pragma unroll
    for (int ks = 0; ks < 16; ++ks) {
      uint2 lo = *(const uint2*)(rp + ks * 32);
      uint2 hi = *(const uint2*)(rp + ks * 32 + 16);
      uint4 t4; t4.x = lo.x; t4.y = lo.y; t4.z = hi.x; t4.w = hi.y;
      af[g][ks] = __builtin_bit_cast(s16x8, t4);
    }
  }
  // --- biases into registers ---
  float bgr[4], bgz[4], bgn[4], bhn[4];
#pragma unroll
  for (int r = 0; r < 4; ++r) {
    bgr[r] = bgx[d * GG + 0 * 512 + u0 + r];
    bgz[r] = bgx[d * GG + 1 * 512 + u0 + r];
    bgn[r] = bgx[d * GG + 2 * 512 + u0 + r];
    bhn[r] = bhn_[d * HH + u0 + r];
  }
  float h[4] = {0.f, 0.f, 0.f, 0.f};

  // hex layout: [buf(2)][dir(2)][ks(16)][nt(2)][lane(64)][elem(8)] bf16
  const size_t HEXBUF = (size_t)2 * 16 * 2 * 64 * 8;     // 32768 elems per buffer
  const size_t wslot = (((size_t)(d * 16 + s) * 2 + nt) * 64 + l) * 8 + 4 * uh;
  {
    uint2 z; z.x = 0u; z.y = 0u;
    *(uint2*)(hex + wslot) = z;                           // zero own slice of buf 0
  }
  wg_barrier(ctr + d, 16u);

  const size_t rbase0 = ((size_t)(d * 16) * 2 + nt) * 64 * 8 + (size_t)l * 8;

  for (int sig = 0; sig < 512; ++sig) {
    const int t = d ? (511 - sig) : sig;

    // gx loads for this step (issued first; overlap with h loads)
    float gxr[4], gxz[4], gxn[4];
    {
      const size_t base = ((size_t)(d * TT + t) * BB + b) * GG + u0;
      if (GXF32) {
        const float* Gp = (const float*)gx_ + base;
        f32x4 vr = *(const f32x4*)(Gp);
        f32x4 vz = *(const f32x4*)(Gp + 512);
        f32x4 vn = *(const f32x4*)(Gp + 1024);
#pragma unroll
        for (int r = 0; r < 4; ++r) { gxr[r] = vr[r]; gxz[r] = vz[r]; gxn[r] = vn[r]; }
      } else {
        const u16* Gp = (const u16*)gx_ + base;
        uint2 vr = *(const uint2*)(Gp);
        uint2 vz = *(const uint2*)(Gp + 512);
        uint2 vn = *(const uint2*)(Gp + 1024);
        gxr[0] = bf2f((u16)vr.x); gxr[1] = bf2f((u16)(vr.x >> 16)); gxr[2] = bf2f((u16)vr.y); gxr[3] = bf2f((u16)(vr.y >> 16));
        gxz[0] = bf2f((u16)vz.x); gxz[1] = bf2f((u16)(vz.x >> 16)); gxz[2] = bf2f((u16)vz.y); gxz[3] = bf2f((u16)(vz.y >> 16));
        gxn[0] = bf2f((u16)vn.x); gxn[1] = bf2f((u16)(vn.x >> 16)); gxn[2] = bf2f((u16)vn.y); gxn[3] = bf2f((u16)(vn.y >> 16));
      }
    }

    // h B-fragments (coalesced dwordx4 from fragment-layout exchange buffer)
    const u16* hb = hex + (size_t)(sig & 1) * HEXBUF + rbase0;
    s16x8 bf[16];
#pragma unroll
    for (int ks = 0; ks < 16; ++ks)
      bf[ks] = __builtin_bit_cast(s16x8, *(const uint4*)(hb + ks * 1024));

    f32x4 a0 = {0.f, 0.f, 0.f, 0.f}, a1 = a0, a2 = a0;
#pragma unroll
    for (int ks = 0; ks < 16; ++ks) {
      a0 = __builtin_amdgcn_mfma_f32_16x16x32_bf16(af[0][ks], bf[ks], a0, 0, 0, 0);
      a1 = __builtin_amdgcn_mfma_f32_16x16x32_bf16(af[1][ks], bf[ks], a1, 0, 0, 0);
      a2 = __builtin_amdgcn_mfma_f32_16x16x32_bf16(af[2][ks], bf[ks], a2, 0, 0, 0);
    }

    u16 hb16[4];
#pragma unroll
    for (int r = 0; r < 4; ++r) {
      float rr = sigmoidf_(gxr[r] + bgr[r] + a0[r]);
      float zz = sigmoidf_(gxz[r] + bgz[r] + a1[r]);
      float nn = tanhf_(gxn[r] + bgn[r] + rr * (a2[r] + bhn[r]));
      h[r] = (1.f - zz) * nn + zz * h[r];
      hb16[r] = f2bf(h[r]);
    }
    uint2 pk; pk.x = (u32)hb16[0] | ((u32)hb16[1] << 16); pk.y = (u32)hb16[2] | ((u32)hb16[3] << 16);
    *(uint2*)(hex + (size_t)((sig + 1) & 1) * HEXBUF + wslot) = pk;

    if (YF32) {   // layer-1 output -> d_out x region, f32
      float4 yv; yv.x = h[0]; yv.y = h[1]; yv.z = h[2]; yv.w = h[3];
      *(float4*)((float*)yout + ((size_t)(b * TT + t) * 1024 + d * 512 + u0)) = yv;
    } else {      // layer-0 output -> A1 fragment buffer (bf16), K-index = d*512+u
      size_t o = (((size_t)(b * 32 + (t >> 4)) * 32 + (d * 16 + s)) * 64 + (l4 * 16 + (t & 15))) * 8 + 4 * uh;
      *(uint2*)((u16*)yout + o) = pk;
    }
    if (sig == 511) {
      float4 fv; fv.x = h[0]; fv.y = h[1]; fv.z = h[2]; fv.w = h[3];
      *(float4*)(finals + (size_t)b * 1024 + d * 512 + u0) = fv;
    }
    if (sig < 511) wg_barrier(ctr + d, 16u * (sig + 2));
  }
}

// ---------------------------------------------------------------------------
extern "C" void kernel_launch(void* const* d_in, const int* in_sizes, int n_in,
                              void* d_out, int out_size, void* d_ws, size_t ws_size,
                              hipStream_t stream) {
  (void)in_sizes; (void)n_in; (void)out_size;
  const float* ctx   = (const float*)d_in[0];
  const float* wih0  = (const float*)d_in[1];
  const float* whh0  = (const float*)d_in[2];
  const float* bih0  = (const float*)d_in[3];
  const float* bhh0  = (const float*)d_in[4];
  const float* wih0r = (const float*)d_in[5];
  const float* whh0r = (const float*)d_in[6];
  const float* bih0r = (const float*)d_in[7];
  const float* bhh0r = (const float*)d_in[8];
  const float* wih1  = (const float*)d_in[9];
  const float* whh1  = (const float*)d_in[10];
  const float* bih1  = (const float*)d_in[11];
  const float* bhh1  = (const float*)d_in[12];
  const float* wih1r = (const float*)d_in[13];
  const float* whh1r = (const float*)d_in[14];
  const float* bih1r = (const float*)d_in[15];
  const float* bhh1r = (const float*)d_in[16];

  char* ws = (char*)d_ws;
  size_t off = 0;
  auto take = [&](size_t bytes) { char* p = ws + off; off += bytes; return p; };
  u16*   a0f  = (u16*)take(16777216);    // A0 frags  [1024][16][64][8] bf16
  u16*   a1f  = (u16*)take(33554432);    // A1 frags  [1024][32][64][8] bf16
  u16*   w0f  = (u16*)take(3145728);     // W0 frags  [192][16][64][8]
  u16*   w1f  = (u16*)take(6291456);     // W1 frags  [192][32][64][8]
  u16*   whhb = (u16*)take(6291456);     // w_hh bf16 [2][2][1536][512]
  float* bgx  = (float*)take(24576);     // [2][2][1536]
  float* bhn  = (float*)take(8192);      // [2][2][512]
  u32*   ctr  = (u32*)take(256);         // 4 barrier counters
  u16*   hex  = (u16*)take(131072);      // h exchange [2][2][16][2][64][8] bf16
  const size_t GXF32_BYTES = 201326592;  // 2*512*32*1536*4
  const size_t GXB16_BYTES = 100663296;
  bool gxf32 = (ws_size >= off + GXF32_BYTES);
  void* gx = (void*)take(gxf32 ? GXF32_BYTES : GXB16_BYTES);

  PrepP P;
  P.ctx = ctx;
  P.wih0 = wih0; P.whh0 = whh0; P.bih0 = bih0; P.bhh0 = bhh0;
  P.wih0r = wih0r; P.whh0r = whh0r; P.bih0r = bih0r; P.bhh0r = bhh0r;
  P.wih1 = wih1; P.whh1 = whh1; P.bih1 = bih1; P.bhh1 = bhh1;
  P.wih1r = wih1r; P.whh1r = whh1r; P.bih1r = bih1r; P.bhh1r = bhh1r;
  P.a0f = a0f; P.w0f = w0f; P.w1f = w1f; P.whh = whhb;
  P.bgx = bgx; P.bhn = bhn; P.ctr = ctr;

  prep_kernel<<<dim3(2048), dim3(256), 0, stream>>>(P);

  float* fin = (float*)d_out + (size_t)MM * 1024;   // final region
  if (gxf32) {
    proj_kernel<true><<<dim3(128, 24), dim3(256), 0, stream>>>(a0f, w0f, gx, 16);
    recur_kernel<true, false><<<dim3(32), dim3(256), 0, stream>>>(
        gx, whhb, bgx, bhn, a1f, fin, hex, ctr);
    proj_kernel<true><<<dim3(128, 24), dim3(256), 0, stream>>>(a1f, w1f, gx, 32);
    recur_kernel<true, true><<<dim3(32), dim3(256), 0, stream>>>(
        gx, whhb + (size_t)2 * GG * HH, bgx + 2 * GG, bhn + 2 * HH, d_out, fin + 32768, hex, ctr + 2);
  } else {
    proj_kernel<false><<<dim3(128, 24), dim3(256), 0, stream>>>(a0f, w0f, gx, 16);
    recur_kernel<false, false><<<dim3(32), dim3(256), 0, stream>>>(
        gx, whhb, bgx, bhn, a1f, fin, hex, ctr);
    proj_kernel<false><<<dim3(128, 24), dim3(256), 0, stream>>>(a1f, w1f, gx, 32);
    recur_kernel<false, true><<<dim3(32), dim3(256), 0, stream>>>(
        gx, whhb + (size_t)2 * GG * HH, bgx + 2 * GG, bhn + 2 * HH, d_out, fin + 32768, hex, ctr + 2);
  }
}

// Round 2
// 3549.613 us; speedup vs baseline: 1.7375x; 1.7375x over previous
//
#include <hip/hip_runtime.h>

typedef unsigned int  u32;
typedef unsigned short u16;
typedef short s16x8 __attribute__((ext_vector_type(8)));
typedef float f32x4 __attribute__((ext_vector_type(4)));

// Problem constants
#define BB 32
#define TT 512
#define HH 512
#define GG 1536          // 3H
#define MM 16384         // B*T

__device__ __forceinline__ u16 f2bf(float f) {
  u32 u = __builtin_bit_cast(u32, f);
  u = u + 0x7FFFu + ((u >> 16) & 1u);   // RNE
  return (u16)(u >> 16);
}
__device__ __forceinline__ float bf2f(u16 h) {
  return __builtin_bit_cast(float, (u32)h << 16);
}
__device__ __forceinline__ float sigmoidf_(float x) { return 1.f / (1.f + __expf(-x)); }
__device__ __forceinline__ float tanhf_(float x)    { return 1.f - 2.f / (__expf(2.f * x) + 1.f); }

// ---------------------------------------------------------------------------
// Fragment layout convention (mfma_f32_16x16x32_bf16), used consistently
// everywhere (any consistent K-permutation of A and B cancels):
//   A (MxK): lane l elem j -> A[16*mb + (l&15)][32*kb + (l>>4)*4 + (j&3) + 16*(j>>2)]
//   B (KxN): lane l elem j -> B[32*kb + (l>>4)*4 + (j&3) + 16*(j>>2)][16*nb + (l&15)]
//   D:       lane l reg  r -> D[(l>>4)*4 + r][l&15]            (m89-verified)
// Global fragment buffers: [blk][kb][lane(64)][elem(8)] bf16, 1KB per (blk,kb).
// ---------------------------------------------------------------------------

struct PrepP {
  const float *ctx;
  const float *wih0, *whh0, *bih0, *bhh0, *wih0r, *whh0r, *bih0r, *bhh0r;
  const float *wih1, *whh1, *bih1, *bhh1, *wih1r, *whh1r, *bih1r, *bhh1r;
  u16 *a0f, *w0f, *w1f, *whh;
  float *bgx, *bhn;
  u32 *ctr;
};

__global__ void prep_kernel(PrepP P) {
  const size_t NA0 = (size_t)MM * 512;          // 8,388,608  A0 frags (K=512)
  const size_t NW0 = (size_t)3072 * 512;        // 1,572,864  W0 frags
  const size_t NW1 = (size_t)3072 * 1024;       // 3,145,728  W1 frags
  const size_t NWH = (size_t)2 * 2 * GG * HH;   // 3,145,728  w_hh bf16 copies
  const size_t NBG = 2 * 2 * (size_t)GG;        // 6144
  const size_t NBN = 2 * 2 * (size_t)HH;        // 2048
  const size_t TOTAL = NA0 + NW0 + NW1 + NWH + NBG + NBN + 4;
  size_t stride = (size_t)gridDim.x * blockDim.x;
  for (size_t i = (size_t)blockIdx.x * blockDim.x + threadIdx.x; i < TOTAL; i += stride) {
    size_t e = i;
    if (e < NA0) {  // context -> A0 fragment buffer (bf16)
      int j = e & 7, l = (e >> 3) & 63, kb = (e >> 9) & 15, mb = (int)(e >> 13);
      int m = mb * 16 + (l & 15);
      int k = kb * 32 + ((l >> 4) << 2) + (j & 3) + ((j >> 2) << 4);
      P.a0f[e] = f2bf(P.ctx[(size_t)m * 512 + k]);
      continue;
    }
    e -= NA0;
    if (e < NW0) {  // w_ih layer0 (both dirs) -> B fragment buffer, N=3072, K=512
      int j = e & 7, l = (e >> 3) & 63, kb = (e >> 9) & 15, nb = (int)(e >> 13);
      int n = nb * 16 + (l & 15);
      int d = (n >= GG) ? 1 : 0, g = n - d * GG;
      int k = kb * 32 + ((l >> 4) << 2) + (j & 3) + ((j >> 2) << 4);
      const float* src = d ? P.wih0r : P.wih0;
      P.w0f[e] = f2bf(src[(size_t)g * 512 + k]);
      continue;
    }
    e -= NW0;
    if (e < NW1) {  // w_ih layer1, K=1024
      int j = e & 7, l = (e >> 3) & 63, kb = (e >> 9) & 31, nb = (int)(e >> 14);
      int n = nb * 16 + (l & 15);
      int d = (n >= GG) ? 1 : 0, g = n - d * GG;
      int k = kb * 32 + ((l >> 4) << 2) + (j & 3) + ((j >> 2) << 4);
      const float* src = d ? P.wih1r : P.wih1;
      P.w1f[e] = f2bf(src[(size_t)g * 1024 + k]);
      continue;
    }
    e -= NW1;
    if (e < NWH) {  // w_hh plain bf16 copies: [layer][dir][1536][512]
      size_t per = (size_t)GG * HH;
      int ld = (int)(e / per); size_t sub = e % per;
      const float* src = (ld == 0) ? P.whh0 : (ld == 1) ? P.whh0r : (ld == 2) ? P.whh1 : P.whh1r;
      P.whh[e] = f2bf(src[sub]);
      continue;
    }
    e -= NWH;
    if (e < NBG) {  // bias_gx[layer][dir][1536] = b_ih + (b_hh for r,z gates)
      int ld = (int)(e / GG), g = (int)(e % GG);
      const float* bi = (ld == 0) ? P.bih0 : (ld == 1) ? P.bih0r : (ld == 2) ? P.bih1 : P.bih1r;
      const float* bh = (ld == 0) ? P.bhh0 : (ld == 1) ? P.bhh0r : (ld == 2) ? P.bhh1 : P.bhh1r;
      P.bgx[e] = bi[g] + ((g < 1024) ? bh[g] : 0.f);
      continue;
    }
    e -= NBG;
    if (e < NBN) {  // bias_hn[layer][dir][512] = b_hh[2H + u]
      int ld = (int)(e / HH), u = (int)(e % HH);
      const float* bh = (ld == 0) ? P.bhh0 : (ld == 1) ? P.bhh0r : (ld == 2) ? P.bhh1 : P.bhh1r;
      P.bhn[e] = bh[1024 + u];
      continue;
    }
    e -= NBN;
    if (e < 4) P.ctr[e] = 0u;
  }
}

// ---------------------------------------------------------------------------
// Projection GEMM: C[M=16384][N=3072] = A[M][K] * W[K][N], bf16 MFMA, f32 out
// scattered into gx[dir][t][b][1536].  128x128 tile, 4 waves (2x2), BK=32.
// ---------------------------------------------------------------------------
template<bool GXF32>
__global__ __launch_bounds__(256, 2) void proj_kernel(const u16* __restrict__ A,
                                                      const u16* __restrict__ W,
                                                      void* __restrict__ gx, int KB) {
  __shared__ uint4 As4[512];
  __shared__ uint4 Bs4[512];
  const int tid = threadIdx.x;
  const int bm = blockIdx.x, bn = blockIdx.y;
  const int l = tid & 63, w = tid >> 6, wm = w >> 1, wn = w & 1;

  f32x4 acc[4][4];
#pragma unroll
  for (int i = 0; i < 4; ++i)
#pragma unroll
    for (int j = 0; j < 4; ++j) acc[i][j] = f32x4{0.f, 0.f, 0.f, 0.f};

  const uint4* GA = (const uint4*)A;
  const uint4* GB = (const uint4*)W;

  for (int kt = 0; kt < KB; ++kt) {
    __syncthreads();
#pragma unroll
    for (int c = 0; c < 2; ++c) {
      int idx = tid * 2 + c;
      int blk = idx >> 6, pos = idx & 63;
      As4[idx] = GA[((size_t)(bm * 8 + blk) * KB + kt) * 64 + pos];
      Bs4[idx] = GB[((size_t)(bn * 8 + blk) * KB + kt) * 64 + pos];
    }
    __syncthreads();
    s16x8 av[4], bv[4];
#pragma unroll
    for (int mf = 0; mf < 4; ++mf) av[mf] = ((const s16x8*)As4)[(wm * 4 + mf) * 64 + l];
#pragma unroll
    for (int nf = 0; nf < 4; ++nf) bv[nf] = ((const s16x8*)Bs4)[(wn * 4 + nf) * 64 + l];
#pragma unroll
    for (int mf = 0; mf < 4; ++mf)
#pragma unroll
      for (int nf = 0; nf < 4; ++nf)
        acc[mf][nf] = __builtin_amdgcn_mfma_f32_16x16x32_bf16(av[mf], bv[nf], acc[mf][nf], 0, 0, 0);
  }

#pragma unroll
  for (int mf = 0; mf < 4; ++mf)
#pragma unroll
    for (int nf = 0; nf < 4; ++nf)
#pragma unroll
      for (int r = 0; r < 4; ++r) {
        int m = bm * 128 + wm * 64 + mf * 16 + (l >> 4) * 4 + r;
        int n = bn * 128 + wn * 64 + nf * 16 + (l & 15);
        int b = m >> 9, t = m & 511;
        int d = (n >= GG) ? 1 : 0, g = n - d * GG;
        size_t o = ((size_t)(d * TT + t) * BB + b) * GG + g;
        float v = acc[mf][nf][r];
        if (GXF32) ((float*)gx)[o] = v;
        else       ((u16*)gx)[o] = f2bf(v);
      }
}

// ---------------------------------------------------------------------------
// Recurrence: 32 WGs (16 per direction), each owns 32 h-units x 32 batches.
// w_hh A-fragments in registers; h exchanged via fragment-layout global buffer
// (double-buffered) using COHERENT (sc0 sc1) stores/loads that write-through /
// read-from the device coherence point — no L2 writeback/invalidate fences.
// Step protocol: coherent h-store -> vmcnt(0) -> syncthreads -> 1 atomic add
// -> (gx prefetch + y-store overlap) -> per-wave spin on counter.
// ---------------------------------------------------------------------------
template<bool GXF32, bool YF32>
__global__ __launch_bounds__(256, 1) void recur_kernel(
    const void* __restrict__ gx_, const u16* __restrict__ whh,
    const float* __restrict__ bgx, const float* __restrict__ bhn_,
    void* __restrict__ yout, float* __restrict__ finals,
    u16* __restrict__ hex, u32* __restrict__ ctr) {
  const int wg = blockIdx.x, d = wg >> 4, s = wg & 15;
  const int tid = threadIdx.x, l = tid & 63, w = tid >> 6;
  const int nt = w & 1, uh = w >> 1;
  const int l4 = l >> 4, lm = l & 15;
  const int b = nt * 16 + lm;
  const int u0 = s * 32 + uh * 16 + l4 * 4;   // first of this lane's 4 h-units (D-side)

  // --- gather w_hh A-fragments into registers ---
  s16x8 af[3][16];
  const u16* wd = whh + (size_t)d * (GG * HH);
#pragma unroll
  for (int g = 0; g < 3; ++g) {
    const int row = g * 512 + s * 32 + uh * 16 + lm;     // A-side row uses lane&15
    const u16* rp = wd + (size_t)row * 512 + l4 * 4;
#pragma unroll
    for (int ks = 0; ks < 16; ++ks) {
      uint2 lo = *(const uint2*)(rp + ks * 32);
      uint2 hi = *(const uint2*)(rp + ks * 32 + 16);
      uint4 t4; t4.x = lo.x; t4.y = lo.y; t4.z = hi.x; t4.w = hi.y;
      af[g][ks] = __builtin_bit_cast(s16x8, t4);
    }
  }
  // --- biases into registers ---
  float bgr[4], bgz[4], bgn[4], bhn[4];
#pragma unroll
  for (int r = 0; r < 4; ++r) {
    bgr[r] = bgx[d * GG + 0 * 512 + u0 + r];
    bgz[r] = bgx[d * GG + 1 * 512 + u0 + r];
    bgn[r] = bgx[d * GG + 2 * 512 + u0 + r];
    bhn[r] = bhn_[d * HH + u0 + r];
  }
  float h[4] = {0.f, 0.f, 0.f, 0.f};
  u32* c = ctr + d;

  // hex layout: [buf(2)][dir(2)][s(16)][nt(2)][lane(64)][elem(8)] bf16
  const u32 HEXB = 65536;   // bytes per buffer
  const u32 wbyte = (u32)(((((d * 16 + s) * 2 + nt) * 64 + l) * 8 + 4 * uh) * 2);
  const u32 rbyte = (u32)((((d * 16) * 2 + nt) * 64 + l) * 8 * 2);

  // --- init: zero own slice of buf0 (coherent) + first barrier ---
  {
    uint2 z; z.x = 0u; z.y = 0u;
    asm volatile("global_store_dwordx2 %0, %1, %2 sc0 sc1"
                 :: "v"(wbyte), "v"(z), "s"(hex) : "memory");
    asm volatile("s_waitcnt vmcnt(0)" ::: "memory");
    __syncthreads();
    if (tid == 0)
      __hip_atomic_fetch_add(c, 1u, __ATOMIC_RELAXED, __HIP_MEMORY_SCOPE_AGENT);
  }

  // --- gx prefetch for sig=0 (overlaps with init spin) ---
  float gxr[4], gxz[4], gxn[4];
  {
    const int t0 = d ? 511 : 0;
    const size_t base = ((size_t)(d * TT + t0) * BB + b) * GG + u0;
    if (GXF32) {
      const float* Gp = (const float*)gx_ + base;
      f32x4 vr = *(const f32x4*)(Gp);
      f32x4 vz = *(const f32x4*)(Gp + 512);
      f32x4 vn = *(const f32x4*)(Gp + 1024);
#pragma unroll
      for (int r = 0; r < 4; ++r) { gxr[r] = vr[r]; gxz[r] = vz[r]; gxn[r] = vn[r]; }
    } else {
      const u16* Gp = (const u16*)gx_ + base;
      uint2 vr = *(const uint2*)(Gp);
      uint2 vz = *(const uint2*)(Gp + 512);
      uint2 vn = *(const uint2*)(Gp + 1024);
      gxr[0] = bf2f((u16)vr.x); gxr[1] = bf2f((u16)(vr.x >> 16)); gxr[2] = bf2f((u16)vr.y); gxr[3] = bf2f((u16)(vr.y >> 16));
      gxz[0] = bf2f((u16)vz.x); gxz[1] = bf2f((u16)(vz.x >> 16)); gxz[2] = bf2f((u16)vz.y); gxz[3] = bf2f((u16)(vz.y >> 16));
      gxn[0] = bf2f((u16)vn.x); gxn[1] = bf2f((u16)(vn.x >> 16)); gxn[2] = bf2f((u16)vn.y); gxn[3] = bf2f((u16)(vn.y >> 16));
    }
  }

  // per-wave spin for init barrier (no trailing syncthreads needed)
  if (l == 0) {
    while (__hip_atomic_load(c, __ATOMIC_RELAXED, __HIP_MEMORY_SCOPE_AGENT) < 16u) {}
  }

  for (int sig = 0; sig < 512; ++sig) {
    const int t = d ? (511 - sig) : sig;

    // A: coherent h-fragment loads from buf[sig&1] (bypass stale L1/L2)
    const u32 ro = (u32)(sig & 1) * HEXB + rbyte;
    uint4 bfr[16];
#pragma unroll
    for (int ks = 0; ks < 16; ++ks)
      asm volatile("global_load_dwordx4 %0, %1, %2 sc0 sc1"
                   : "=v"(bfr[ks]) : "v"(ro + ks * 2048), "s"(hex) : "memory");

    // B/C: staged waits + MFMA chains
    f32x4 a0 = {0.f, 0.f, 0.f, 0.f}, a1 = a0, a2 = a0;
    asm volatile("s_waitcnt vmcnt(8)" ::: "memory");
    __builtin_amdgcn_sched_barrier(0);
#pragma unroll
    for (int ks = 0; ks < 8; ++ks) {
      s16x8 bfv = __builtin_bit_cast(s16x8, bfr[ks]);
      a0 = __builtin_amdgcn_mfma_f32_16x16x32_bf16(af[0][ks], bfv, a0, 0, 0, 0);
      a1 = __builtin_amdgcn_mfma_f32_16x16x32_bf16(af[1][ks], bfv, a1, 0, 0, 0);
      a2 = __builtin_amdgcn_mfma_f32_16x16x32_bf16(af[2][ks], bfv, a2, 0, 0, 0);
    }
    asm volatile("s_waitcnt vmcnt(0)" ::: "memory");
    __builtin_amdgcn_sched_barrier(0);
#pragma unroll
    for (int ks = 8; ks < 16; ++ks) {
      s16x8 bfv = __builtin_bit_cast(s16x8, bfr[ks]);
      a0 = __builtin_amdgcn_mfma_f32_16x16x32_bf16(af[0][ks], bfv, a0, 0, 0, 0);
      a1 = __builtin_amdgcn_mfma_f32_16x16x32_bf16(af[1][ks], bfv, a1, 0, 0, 0);
      a2 = __builtin_amdgcn_mfma_f32_16x16x32_bf16(af[2][ks], bfv, a2, 0, 0, 0);
    }

    // D: gates
    u16 hb16[4];
#pragma unroll
    for (int r = 0; r < 4; ++r) {
      float rr = sigmoidf_(gxr[r] + bgr[r] + a0[r]);
      float zz = sigmoidf_(gxz[r] + bgz[r] + a1[r]);
      float nn = tanhf_(gxn[r] + bgn[r] + rr * (a2[r] + bhn[r]));
      h[r] = (1.f - zz) * nn + zz * h[r];
      hb16[r] = f2bf(h[r]);
    }
    uint2 pk; pk.x = (u32)hb16[0] | ((u32)hb16[1] << 16); pk.y = (u32)hb16[2] | ((u32)hb16[3] << 16);

    if (sig < 511) {
      // E/F/G/H: coherent h-store -> ack -> syncthreads -> single atomic add
      const u32 wo = (u32)((sig + 1) & 1) * HEXB + wbyte;
      asm volatile("global_store_dwordx2 %0, %1, %2 sc0 sc1"
                   :: "v"(wo), "v"(pk), "s"(hex) : "memory");
      asm volatile("s_waitcnt vmcnt(0)" ::: "memory");
      __syncthreads();
      if (tid == 0)
        __hip_atomic_fetch_add(c, 1u, __ATOMIC_RELAXED, __HIP_MEMORY_SCOPE_AGENT);
    }

    // I: y-store + gx prefetch for next step (overlap with spin)
    if (YF32) {
      float4 yv; yv.x = h[0]; yv.y = h[1]; yv.z = h[2]; yv.w = h[3];
      *(float4*)((float*)yout + ((size_t)(b * TT + t) * 1024 + d * 512 + u0)) = yv;
    } else {
      size_t o = (((size_t)(b * 32 + (t >> 4)) * 32 + (d * 16 + s)) * 64 + (l4 * 16 + (t & 15))) * 8 + 4 * uh;
      *(uint2*)((u16*)yout + o) = pk;
    }
    if (sig == 511) {
      float4 fv; fv.x = h[0]; fv.y = h[1]; fv.z = h[2]; fv.w = h[3];
      *(float4*)(finals + (size_t)b * 1024 + d * 512 + u0) = fv;
      break;
    }
    {
      const int t2 = d ? (511 - (sig + 1)) : (sig + 1);
      const size_t base = ((size_t)(d * TT + t2) * BB + b) * GG + u0;
      if (GXF32) {
        const float* Gp = (const float*)gx_ + base;
        f32x4 vr = *(const f32x4*)(Gp);
        f32x4 vz = *(const f32x4*)(Gp + 512);
        f32x4 vn = *(const f32x4*)(Gp + 1024);
#pragma unroll
        for (int r = 0; r < 4; ++r) { gxr[r] = vr[r]; gxz[r] = vz[r]; gxn[r] = vn[r]; }
      } else {
        const u16* Gp = (const u16*)gx_ + base;
        uint2 vr = *(const uint2*)(Gp);
        uint2 vz = *(const uint2*)(Gp + 512);
        uint2 vn = *(const uint2*)(Gp + 1024);
        gxr[0] = bf2f((u16)vr.x); gxr[1] = bf2f((u16)(vr.x >> 16)); gxr[2] = bf2f((u16)vr.y); gxr[3] = bf2f((u16)(vr.y >> 16));
        gxz[0] = bf2f((u16)vz.x); gxz[1] = bf2f((u16)(vz.x >> 16)); gxz[2] = bf2f((u16)vz.y); gxz[3] = bf2f((u16)(vz.y >> 16));
        gxn[0] = bf2f((u16)vn.x); gxn[1] = bf2f((u16)(vn.x >> 16)); gxn[2] = bf2f((u16)vn.y); gxn[3] = bf2f((u16)(vn.y >> 16));
      }
    }

    // J: per-wave spin on counter (each wave proceeds independently)
    if (l == 0) {
      const u32 tgt = 16u * (u32)(sig + 2);
      while (__hip_atomic_load(c, __ATOMIC_RELAXED, __HIP_MEMORY_SCOPE_AGENT) < tgt) {}
    }
  }
}

// ---------------------------------------------------------------------------
extern "C" void kernel_launch(void* const* d_in, const int* in_sizes, int n_in,
                              void* d_out, int out_size, void* d_ws, size_t ws_size,
                              hipStream_t stream) {
  (void)in_sizes; (void)n_in; (void)out_size;
  const float* ctx   = (const float*)d_in[0];
  const float* wih0  = (const float*)d_in[1];
  const float* whh0  = (const float*)d_in[2];
  const float* bih0  = (const float*)d_in[3];
  const float* bhh0  = (const float*)d_in[4];
  const float* wih0r = (const float*)d_in[5];
  const float* whh0r = (const float*)d_in[6];
  const float* bih0r = (const float*)d_in[7];
  const float* bhh0r = (const float*)d_in[8];
  const float* wih1  = (const float*)d_in[9];
  const float* whh1  = (const float*)d_in[10];
  const float* bih1  = (const float*)d_in[11];
  const float* bhh1  = (const float*)d_in[12];
  const float* wih1r = (const float*)d_in[13];
  const float* whh1r = (const float*)d_in[14];
  const float* bih1r = (const float*)d_in[15];
  const float* bhh1r = (const float*)d_in[16];

  char* ws = (char*)d_ws;
  size_t off = 0;
  auto take = [&](size_t bytes) { char* p = ws + off; off += bytes; return p; };
  u16*   a0f  = (u16*)take(16777216);    // A0 frags  [1024][16][64][8] bf16
  u16*   a1f  = (u16*)take(33554432);    // A1 frags  [1024][32][64][8] bf16
  u16*   w0f  = (u16*)take(3145728);     // W0 frags  [192][16][64][8]
  u16*   w1f  = (u16*)take(6291456);     // W1 frags  [192][32][64][8]
  u16*   whhb = (u16*)take(6291456);     // w_hh bf16 [2][2][1536][512]
  float* bgx  = (float*)take(24576);     // [2][2][1536]
  float* bhn  = (float*)take(8192);      // [2][2][512]
  u32*   ctr  = (u32*)take(256);         // 4 barrier counters
  u16*   hex  = (u16*)take(131072);      // h exchange [2][2][16][2][64][8] bf16
  const size_t GXF32_BYTES = 201326592;  // 2*512*32*1536*4
  const size_t GXB16_BYTES = 100663296;
  bool gxf32 = (ws_size >= off + GXF32_BYTES);
  void* gx = (void*)take(gxf32 ? GXF32_BYTES : GXB16_BYTES);

  PrepP P;
  P.ctx = ctx;
  P.wih0 = wih0; P.whh0 = whh0; P.bih0 = bih0; P.bhh0 = bhh0;
  P.wih0r = wih0r; P.whh0r = whh0r; P.bih0r = bih0r; P.bhh0r = bhh0r;
  P.wih1 = wih1; P.whh1 = whh1; P.bih1 = bih1; P.bhh1 = bhh1;
  P.wih1r = wih1r; P.whh1r = whh1r; P.bih1r = bih1r; P.bhh1r = bhh1r;
  P.a0f = a0f; P.w0f = w0f; P.w1f = w1f; P.whh = whhb;
  P.bgx = bgx; P.bhn = bhn; P.ctr = ctr;

  prep_kernel<<<dim3(2048), dim3(256), 0, stream>>>(P);

  float* fin = (float*)d_out + (size_t)MM * 1024;   // final region
  if (gxf32) {
    proj_kernel<true><<<dim3(128, 24), dim3(256), 0, stream>>>(a0f, w0f, gx, 16);
    recur_kernel<true, false><<<dim3(32), dim3(256), 0, stream>>>(
        gx, whhb, bgx, bhn, a1f, fin, hex, ctr);
    proj_kernel<true><<<dim3(128, 24), dim3(256), 0, stream>>>(a1f, w1f, gx, 32);
    recur_kernel<true, true><<<dim3(32), dim3(256), 0, stream>>>(
        gx, whhb + (size_t)2 * GG * HH, bgx + 2 * GG, bhn + 2 * HH, d_out, fin + 32768, hex, ctr + 2);
  } else {
    proj_kernel<false><<<dim3(128, 24), dim3(256), 0, stream>>>(a0f, w0f, gx, 16);
    recur_kernel<false, false><<<dim3(32), dim3(256), 0, stream>>>(
        gx, whhb, bgx, bhn, a1f, fin, hex, ctr);
    proj_kernel<false><<<dim3(128, 24), dim3(256), 0, stream>>>(a1f, w1f, gx, 32);
    recur_kernel<false, true><<<dim3(32), dim3(256), 0, stream>>>(
        gx, whhb + (size_t)2 * GG * HH, bgx + 2 * GG, bhn + 2 * HH, d_out, fin + 32768, hex, ctr + 2);
  }
}

// Round 7
// 3322.942 us; speedup vs baseline: 1.8560x; 1.0682x over previous
//
#include <hip/hip_runtime.h>

typedef unsigned int  u32;
typedef unsigned short u16;
typedef short s16x8 __attribute__((ext_vector_type(8)));
typedef float f32x4 __attribute__((ext_vector_type(4)));
typedef u32 u32x2 __attribute__((ext_vector_type(2)));
typedef u32 u32x4 __attribute__((ext_vector_type(4)));

// Problem constants
#define BB 32
#define TT 512
#define HH 512
#define GG 1536          // 3H
#define MM 16384         // B*T

__device__ __forceinline__ u16 f2bf(float f) {
  u32 u = __builtin_bit_cast(u32, f);
  u = u + 0x7FFFu + ((u >> 16) & 1u);   // RNE
  return (u16)(u >> 16);
}
__device__ __forceinline__ float bf2f(u16 h) {
  return __builtin_bit_cast(float, (u32)h << 16);
}
__device__ __forceinline__ float sigmoidf_(float x) { return 1.f / (1.f + __expf(-x)); }
__device__ __forceinline__ float tanhf_(float x)    { return 1.f - 2.f / (__expf(2.f * x) + 1.f); }

// ---------------------------------------------------------------------------
// Fragment layout convention (mfma_f32_16x16x32_bf16), used consistently
// everywhere (any consistent K-permutation of A and B cancels):
//   A (MxK): lane l elem j -> A[16*mb + (l&15)][32*kb + (l>>4)*4 + (j&3) + 16*(j>>2)]
//   B (KxN): lane l elem j -> B[32*kb + (l>>4)*4 + (j&3) + 16*(j>>2)][16*nb + (l&15)]
//   D:       lane l reg  r -> D[(l>>4)*4 + r][l&15]            (m89-verified)
// ---------------------------------------------------------------------------

struct PrepP {
  const float *ctx;
  const float *wih0, *whh0, *bih0, *bhh0, *wih0r, *whh0r, *bih0r, *bhh0r;
  const float *wih1, *whh1, *bih1, *bhh1, *wih1r, *whh1r, *bih1r, *bhh1r;
  u16 *a0f, *w0f, *w1f, *whh;
  float *bgx, *bhn;
  u32 *flg;
};

__global__ void prep_kernel(PrepP P) {
  const size_t NA0 = (size_t)MM * 512;          // A0 frags
  const size_t NW0 = (size_t)3072 * 512;        // W0 frags
  const size_t NW1 = (size_t)3072 * 1024;       // W1 frags
  const size_t NWH = (size_t)2 * 2 * GG * HH;   // w_hh bf16 copies
  const size_t NBG = 2 * 2 * (size_t)GG;
  const size_t NBN = 2 * 2 * (size_t)HH;
  const size_t NFL = 256;                       // 2 recurs x 2 dirs x 64 flag words
  const size_t TOTAL = NA0 + NW0 + NW1 + NWH + NBG + NBN + NFL;
  size_t stride = (size_t)gridDim.x * blockDim.x;
  for (size_t i = (size_t)blockIdx.x * blockDim.x + threadIdx.x; i < TOTAL; i += stride) {
    size_t e = i;
    if (e < NA0) {
      int j = e & 7, l = (e >> 3) & 63, kb = (e >> 9) & 15, mb = (int)(e >> 13);
      int m = mb * 16 + (l & 15);
      int k = kb * 32 + ((l >> 4) << 2) + (j & 3) + ((j >> 2) << 4);
      P.a0f[e] = f2bf(P.ctx[(size_t)m * 512 + k]);
      continue;
    }
    e -= NA0;
    if (e < NW0) {
      int j = e & 7, l = (e >> 3) & 63, kb = (e >> 9) & 15, nb = (int)(e >> 13);
      int n = nb * 16 + (l & 15);
      int d = (n >= GG) ? 1 : 0, g = n - d * GG;
      int k = kb * 32 + ((l >> 4) << 2) + (j & 3) + ((j >> 2) << 4);
      const float* src = d ? P.wih0r : P.wih0;
      P.w0f[e] = f2bf(src[(size_t)g * 512 + k]);
      continue;
    }
    e -= NW0;
    if (e < NW1) {
      int j = e & 7, l = (e >> 3) & 63, kb = (e >> 9) & 31, nb = (int)(e >> 14);
      int n = nb * 16 + (l & 15);
      int d = (n >= GG) ? 1 : 0, g = n - d * GG;
      int k = kb * 32 + ((l >> 4) << 2) + (j & 3) + ((j >> 2) << 4);
      const float* src = d ? P.wih1r : P.wih1;
      P.w1f[e] = f2bf(src[(size_t)g * 1024 + k]);
      continue;
    }
    e -= NW1;
    if (e < NWH) {
      size_t per = (size_t)GG * HH;
      int ld = (int)(e / per); size_t sub = e % per;
      const float* src = (ld == 0) ? P.whh0 : (ld == 1) ? P.whh0r : (ld == 2) ? P.whh1 : P.whh1r;
      P.whh[e] = f2bf(src[sub]);
      continue;
    }
    e -= NWH;
    if (e < NBG) {
      int ld = (int)(e / GG), g = (int)(e % GG);
      const float* bi = (ld == 0) ? P.bih0 : (ld == 1) ? P.bih0r : (ld == 2) ? P.bih1 : P.bih1r;
      const float* bh = (ld == 0) ? P.bhh0 : (ld == 1) ? P.bhh0r : (ld == 2) ? P.bhh1 : P.bhh1r;
      P.bgx[e] = bi[g] + ((g < 1024) ? bh[g] : 0.f);
      continue;
    }
    e -= NBG;
    if (e < NBN) {
      int ld = (int)(e / HH), u = (int)(e % HH);
      const float* bh = (ld == 0) ? P.bhh0 : (ld == 1) ? P.bhh0r : (ld == 2) ? P.bhh1 : P.bhh1r;
      P.bhn[e] = bh[1024 + u];
      continue;
    }
    e -= NBN;
    if (e < NFL) { P.flg[e] = 0u; continue; }
  }
}

// ---------------------------------------------------------------------------
// Projection GEMM (unchanged, R2-proven): C[16384][3072] = A*W, bf16 MFMA.
// ---------------------------------------------------------------------------
template<bool GXF32>
__global__ __launch_bounds__(256, 2) void proj_kernel(const u16* __restrict__ A,
                                                      const u16* __restrict__ W,
                                                      void* __restrict__ gx, int KB) {
  __shared__ uint4 As4[512];
  __shared__ uint4 Bs4[512];
  const int tid = threadIdx.x;
  const int bm = blockIdx.x, bn = blockIdx.y;
  const int l = tid & 63, w = tid >> 6, wm = w >> 1, wn = w & 1;

  f32x4 acc[4][4];
#pragma unroll
  for (int i = 0; i < 4; ++i)
#pragma unroll
    for (int j = 0; j < 4; ++j) acc[i][j] = f32x4{0.f, 0.f, 0.f, 0.f};

  const uint4* GA = (const uint4*)A;
  const uint4* GB = (const uint4*)W;

  for (int kt = 0; kt < KB; ++kt) {
    __syncthreads();
#pragma unroll
    for (int c = 0; c < 2; ++c) {
      int idx = tid * 2 + c;
      int blk = idx >> 6, pos = idx & 63;
      As4[idx] = GA[((size_t)(bm * 8 + blk) * KB + kt) * 64 + pos];
      Bs4[idx] = GB[((size_t)(bn * 8 + blk) * KB + kt) * 64 + pos];
    }
    __syncthreads();
    s16x8 av[4], bv[4];
#pragma unroll
    for (int mf = 0; mf < 4; ++mf) av[mf] = ((const s16x8*)As4)[(wm * 4 + mf) * 64 + l];
#pragma unroll
    for (int nf = 0; nf < 4; ++nf) bv[nf] = ((const s16x8*)Bs4)[(wn * 4 + nf) * 64 + l];
#pragma unroll
    for (int mf = 0; mf < 4; ++mf)
#pragma unroll
      for (int nf = 0; nf < 4; ++nf)
        acc[mf][nf] = __builtin_amdgcn_mfma_f32_16x16x32_bf16(av[mf], bv[nf], acc[mf][nf], 0, 0, 0);
  }

#pragma unroll
  for (int mf = 0; mf < 4; ++mf)
#pragma unroll
    for (int nf = 0; nf < 4; ++nf)
#pragma unroll
      for (int r = 0; r < 4; ++r) {
        int m = bm * 128 + wm * 64 + mf * 16 + (l >> 4) * 4 + r;
        int n = bn * 128 + wn * 64 + nf * 16 + (l & 15);
        int b = m >> 9, t = m & 511;
        int d = (n >= GG) ? 1 : 0, g = n - d * GG;
        size_t o = ((size_t)(d * TT + t) * BB + b) * GG + g;
        float v = acc[mf][nf][r];
        if (GXF32) ((float*)gx)[o] = v;
        else       ((u16*)gx)[o] = f2bf(v);
      }
}

// ---------------------------------------------------------------------------
// Device-scope (sc0 sc1) data helpers — R2-proven visibility class.
// ---------------------------------------------------------------------------
__device__ __forceinline__ u32x4 hld16(const u16* p, u32 off) {
  u32x4 r;
  asm volatile("global_load_dwordx4 %0, %1, %2 sc0 sc1"
               : "=v"(r) : "v"(off), "s"(p) : "memory");
  return r;
}
__device__ __forceinline__ void hst8(u16* p, u32 off, u32x2 v) {
  asm volatile("global_store_dwordx2 %0, %1, %2 sc0 sc1"
               :: "v"(off), "v"(v), "s"(p) : "memory");
}

// ---------------------------------------------------------------------------
// Recurrence: 32 WGs (16/dir).  R2-proven protocol with two measured costs
// removed: per-WAVE atomic flag (64 words/dir, no RMW contention) replaces the
// single shared counter, and no __syncthreads (waves publish independently).
// Step:  [poll 64 flags >= sig via per-lane agent atomic loads]
//        -> one-shot h loads (sc0 sc1, staged vmcnt into MFMA)
//        -> gates -> h-store (sc0 sc1) -> vmcnt(0) -> lane0 atomic flag=sig+1
//        -> y store -> gx prefetch (overlaps others' publish + next poll).
// hex layout (R2 verbatim): [buf(2)][dir(2)][s(16)][nt(2)][lane(64)][elem(8)].
// ---------------------------------------------------------------------------
template<bool GXF32, bool YF32>
__global__ __launch_bounds__(256, 1) void recur_kernel(
    const void* __restrict__ gx_, const u16* __restrict__ whh,
    const float* __restrict__ bgx, const float* __restrict__ bhn_,
    void* __restrict__ yout, float* __restrict__ finals,
    u16* __restrict__ hex, u32* __restrict__ flg) {
  const int wg = blockIdx.x, d = wg >> 4, s = wg & 15;
  const int tid = threadIdx.x, l = tid & 63, w = tid >> 6;
  const int nt = w & 1, uh = w >> 1;
  const int l4 = l >> 4, lm = l & 15;
  const int b = nt * 16 + lm;
  const int u0 = s * 32 + uh * 16 + l4 * 4;   // first of this lane's 4 h-units

  // --- w_hh A-fragments into registers ---
  s16x8 af[3][16];
  const u16* wd = whh + (size_t)d * (GG * HH);
#pragma unroll
  for (int g = 0; g < 3; ++g) {
    const int row = g * 512 + s * 32 + uh * 16 + lm;   // A-side row uses lane&15
    const u16* rp = wd + (size_t)row * 512 + l4 * 4;
#pragma unroll
    for (int ks = 0; ks < 16; ++ks) {
      u32 lo0 = *(const u32*)(rp + ks * 32);
      u32 lo1 = *(const u32*)(rp + ks * 32 + 2);
      u32 hi0 = *(const u32*)(rp + ks * 32 + 16);
      u32 hi1 = *(const u32*)(rp + ks * 32 + 18);
      u32x4 t4; t4.x = lo0; t4.y = lo1; t4.z = hi0; t4.w = hi1;
      af[g][ks] = __builtin_bit_cast(s16x8, t4);
    }
  }
  float bgr[4], bgz[4], bgn[4], bhn[4];
#pragma unroll
  for (int r = 0; r < 4; ++r) {
    bgr[r] = bgx[d * GG + 0 * 512 + u0 + r];
    bgz[r] = bgx[d * GG + 1 * 512 + u0 + r];
    bgn[r] = bgx[d * GG + 2 * 512 + u0 + r];
    bhn[r] = bhn_[d * HH + u0 + r];
  }
  float h[4] = {0.f, 0.f, 0.f, 0.f};

  const u32 HEXB = 65536;   // bytes per buffer
  const u32 wbyte = (u32)(((((d * 16 + s) * 2 + nt) * 64 + l) * 8 + 4 * uh) * 2);
  const u32 rbyte = (u32)(((d * 32 + nt) * 64 + l) * 16);
  u32* fdir = flg + d * 64;
  const int fw = s * 4 + w;

  // gx registers, prologue load for sig=0
  float gxr[4], gxz[4], gxn[4];
  {
    const int t0 = d ? 511 : 0;
    const size_t base = ((size_t)(d * TT + t0) * BB + b) * GG + u0;
    if (GXF32) {
      const float* Gp = (const float*)gx_ + base;
      f32x4 vr = *(const f32x4*)(Gp);
      f32x4 vz = *(const f32x4*)(Gp + 512);
      f32x4 vn = *(const f32x4*)(Gp + 1024);
#pragma unroll
      for (int r = 0; r < 4; ++r) { gxr[r] = vr[r]; gxz[r] = vz[r]; gxn[r] = vn[r]; }
    } else {
      const u32* Gp = (const u32*)((const u16*)gx_ + base);
      u32 vr0 = Gp[0], vr1 = Gp[1], vz0 = Gp[256], vz1 = Gp[257], vn0 = Gp[512], vn1 = Gp[513];
      gxr[0] = bf2f((u16)vr0); gxr[1] = bf2f((u16)(vr0 >> 16)); gxr[2] = bf2f((u16)vr1); gxr[3] = bf2f((u16)(vr1 >> 16));
      gxz[0] = bf2f((u16)vz0); gxz[1] = bf2f((u16)(vz0 >> 16)); gxz[2] = bf2f((u16)vz1); gxz[3] = bf2f((u16)(vz1 >> 16));
      gxn[0] = bf2f((u16)vn0); gxn[1] = bf2f((u16)(vn0 >> 16)); gxn[2] = bf2f((u16)vn1); gxn[3] = bf2f((u16)(vn1 >> 16));
    }
  }

  for (int sig = 0; sig < 512; ++sig) {
    const int t = d ? (511 - sig) : sig;

    f32x4 a0 = {0.f, 0.f, 0.f, 0.f}, a1 = a0, a2 = a0;
    if (sig > 0) {
      // 1. poll: all 64 flag words of this direction >= sig (per-lane atomic loads)
      u32 v;
      do {
        v = __hip_atomic_load(fdir + l, __ATOMIC_RELAXED, __HIP_MEMORY_SCOPE_AGENT);
      } while (!__all((int)v >= sig));

      // 2. one-shot h loads from buf[sig&1] (fresh read after readiness — R2-proven)
      const u32 ro = (u32)(sig & 1) * HEXB + rbyte;
      u32x4 bfr[16];
#pragma unroll
      for (int ks = 0; ks < 16; ++ks)
        bfr[ks] = hld16(hex, ro + (u32)ks * 2048);

      // 3. staged MFMA (R2-verbatim; sched_barrier pins post-wait — rule 18)
      asm volatile("s_waitcnt vmcnt(8)" ::: "memory");
      __builtin_amdgcn_sched_barrier(0);
#pragma unroll
      for (int ks = 0; ks < 8; ++ks) {
        s16x8 bv = __builtin_bit_cast(s16x8, bfr[ks]);
        a0 = __builtin_amdgcn_mfma_f32_16x16x32_bf16(af[0][ks], bv, a0, 0, 0, 0);
        a1 = __builtin_amdgcn_mfma_f32_16x16x32_bf16(af[1][ks], bv, a1, 0, 0, 0);
        a2 = __builtin_amdgcn_mfma_f32_16x16x32_bf16(af[2][ks], bv, a2, 0, 0, 0);
      }
      asm volatile("s_waitcnt vmcnt(0)" ::: "memory");
      __builtin_amdgcn_sched_barrier(0);
#pragma unroll
      for (int ks = 8; ks < 16; ++ks) {
        s16x8 bv = __builtin_bit_cast(s16x8, bfr[ks]);
        a0 = __builtin_amdgcn_mfma_f32_16x16x32_bf16(af[0][ks], bv, a0, 0, 0, 0);
        a1 = __builtin_amdgcn_mfma_f32_16x16x32_bf16(af[1][ks], bv, a1, 0, 0, 0);
        a2 = __builtin_amdgcn_mfma_f32_16x16x32_bf16(af[2][ks], bv, a2, 0, 0, 0);
      }
    }

    // 4. gates
    u16 hb16[4];
#pragma unroll
    for (int r = 0; r < 4; ++r) {
      float rr = sigmoidf_(gxr[r] + bgr[r] + a0[r]);
      float zz = sigmoidf_(gxz[r] + bgz[r] + a1[r]);
      float nn = tanhf_(gxn[r] + bgn[r] + rr * (a2[r] + bhn[r]));
      h[r] = (1.f - zz) * nn + zz * h[r];
      hb16[r] = f2bf(h[r]);
    }
    u32x2 pk; pk.x = (u32)hb16[0] | ((u32)hb16[1] << 16); pk.y = (u32)hb16[2] | ((u32)hb16[3] << 16);

    // 5. publish: data store -> vmcnt(0) drain -> per-wave atomic flag
    if (sig < 511) {
      hst8(hex, (u32)((sig + 1) & 1) * HEXB + wbyte, pk);
      asm volatile("s_waitcnt vmcnt(0)" ::: "memory");
      if (l == 0)
        __hip_atomic_store(fdir + fw, (u32)(sig + 1), __ATOMIC_RELAXED, __HIP_MEMORY_SCOPE_AGENT);
    }

    // 6. y output
    if (YF32) {
      f32x4 yv; yv.x = h[0]; yv.y = h[1]; yv.z = h[2]; yv.w = h[3];
      *(f32x4*)((float*)yout + ((size_t)(b * TT + t) * 1024 + d * 512 + u0)) = yv;
    } else {
      size_t o = (((size_t)(b * 32 + (t >> 4)) * 32 + (d * 16 + s)) * 64 + (l4 * 16 + (t & 15))) * 8 + 4 * uh;
      *(u32x2*)((u16*)yout + o) = pk;
    }
    if (sig == 511) {
      f32x4 fv; fv.x = h[0]; fv.y = h[1]; fv.z = h[2]; fv.w = h[3];
      *(f32x4*)(finals + (size_t)b * 1024 + d * 512 + u0) = fv;
      break;
    }

    // 7. gx prefetch for sig+1 (overlaps others' publish and our next poll)
    {
      const int t2 = d ? (511 - (sig + 1)) : (sig + 1);
      const size_t base = ((size_t)(d * TT + t2) * BB + b) * GG + u0;
      if (GXF32) {
        const float* Gp = (const float*)gx_ + base;
        f32x4 vr = *(const f32x4*)(Gp);
        f32x4 vz = *(const f32x4*)(Gp + 512);
        f32x4 vn = *(const f32x4*)(Gp + 1024);
#pragma unroll
        for (int r = 0; r < 4; ++r) { gxr[r] = vr[r]; gxz[r] = vz[r]; gxn[r] = vn[r]; }
      } else {
        const u32* Gp = (const u32*)((const u16*)gx_ + base);
        u32 vr0 = Gp[0], vr1 = Gp[1], vz0 = Gp[256], vz1 = Gp[257], vn0 = Gp[512], vn1 = Gp[513];
        gxr[0] = bf2f((u16)vr0); gxr[1] = bf2f((u16)(vr0 >> 16)); gxr[2] = bf2f((u16)vr1); gxr[3] = bf2f((u16)(vr1 >> 16));
        gxz[0] = bf2f((u16)vz0); gxz[1] = bf2f((u16)(vz0 >> 16)); gxz[2] = bf2f((u16)vz1); gxz[3] = bf2f((u16)(vz1 >> 16));
        gxn[0] = bf2f((u16)vn0); gxn[1] = bf2f((u16)(vn0 >> 16)); gxn[2] = bf2f((u16)vn1); gxn[3] = bf2f((u16)(vn1 >> 16));
      }
    }
  }
}

// ---------------------------------------------------------------------------
extern "C" void kernel_launch(void* const* d_in, const int* in_sizes, int n_in,
                              void* d_out, int out_size, void* d_ws, size_t ws_size,
                              hipStream_t stream) {
  (void)in_sizes; (void)n_in; (void)out_size;
  const float* ctx   = (const float*)d_in[0];
  const float* wih0  = (const float*)d_in[1];
  const float* whh0  = (const float*)d_in[2];
  const float* bih0  = (const float*)d_in[3];
  const float* bhh0  = (const float*)d_in[4];
  const float* wih0r = (const float*)d_in[5];
  const float* whh0r = (const float*)d_in[6];
  const float* bih0r = (const float*)d_in[7];
  const float* bhh0r = (const float*)d_in[8];
  const float* wih1  = (const float*)d_in[9];
  const float* whh1  = (const float*)d_in[10];
  const float* bih1  = (const float*)d_in[11];
  const float* bhh1  = (const float*)d_in[12];
  const float* wih1r = (const float*)d_in[13];
  const float* whh1r = (const float*)d_in[14];
  const float* bih1r = (const float*)d_in[15];
  const float* bhh1r = (const float*)d_in[16];

  char* ws = (char*)d_ws;
  size_t off = 0;
  auto take = [&](size_t bytes) { char* p = ws + off; off += bytes; return p; };
  u16*   a0f  = (u16*)take(16777216);    // A0 frags
  u16*   a1f  = (u16*)take(33554432);    // A1 frags
  u16*   w0f  = (u16*)take(3145728);     // W0 frags
  u16*   w1f  = (u16*)take(6291456);     // W1 frags
  u16*   whhb = (u16*)take(6291456);     // w_hh bf16 [2][2][1536][512]
  float* bgx  = (float*)take(24576);     // [2][2][1536]
  float* bhn  = (float*)take(8192);      // [2][2][512]
  u32*   flg  = (u32*)take(1024);        // 2 recurs x 2 dirs x 64 flag words
  u16*   hexA = (u16*)take(131072);      // recur0 h exchange (2 bufs x 64KB)
  u16*   hexB = (u16*)take(131072);      // recur1 h exchange
  const size_t GXF32_BYTES = 201326592;  // 2*512*32*1536*4
  const size_t GXB16_BYTES = 100663296;
  bool gxf32 = (ws_size >= off + GXF32_BYTES);
  void* gx = (void*)take(gxf32 ? GXF32_BYTES : GXB16_BYTES);

  PrepP P;
  P.ctx = ctx;
  P.wih0 = wih0; P.whh0 = whh0; P.bih0 = bih0; P.bhh0 = bhh0;
  P.wih0r = wih0r; P.whh0r = whh0r; P.bih0r = bih0r; P.bhh0r = bhh0r;
  P.wih1 = wih1; P.whh1 = whh1; P.bih1 = bih1; P.bhh1 = bhh1;
  P.wih1r = wih1r; P.whh1r = whh1r; P.bih1r = bih1r; P.bhh1r = bhh1r;
  P.a0f = a0f; P.w0f = w0f; P.w1f = w1f; P.whh = whhb;
  P.bgx = bgx; P.bhn = bhn; P.flg = flg;

  prep_kernel<<<dim3(2048), dim3(256), 0, stream>>>(P);

  float* fin = (float*)d_out + (size_t)MM * 1024;
  if (gxf32) {
    proj_kernel<true><<<dim3(128, 24), dim3(256), 0, stream>>>(a0f, w0f, gx, 16);
    recur_kernel<true, false><<<dim3(32), dim3(256), 0, stream>>>(
        gx, whhb, bgx, bhn, a1f, fin, hexA, flg);
    proj_kernel<true><<<dim3(128, 24), dim3(256), 0, stream>>>(a1f, w1f, gx, 32);
    recur_kernel<true, true><<<dim3(32), dim3(256), 0, stream>>>(
        gx, whhb + (size_t)2 * GG * HH, bgx + 2 * GG, bhn + 2 * HH, d_out, fin + 32768,
        hexB, flg + 128);
  } else {
    proj_kernel<false><<<dim3(128, 24), dim3(256), 0, stream>>>(a0f, w0f, gx, 16);
    recur_kernel<false, false><<<dim3(32), dim3(256), 0, stream>>>(
        gx, whhb, bgx, bhn, a1f, fin, hexA, flg);
    proj_kernel<false><<<dim3(128, 24), dim3(256), 0, stream>>>(a1f, w1f, gx, 32);
    recur_kernel<false, true><<<dim3(32), dim3(256), 0, stream>>>(
        gx, whhb + (size_t)2 * GG * HH, bgx + 2 * GG, bhn + 2 * HH, d_out, fin + 32768,
        hexB, flg + 128);
  }
}